// Round 2
// baseline (145.091 us; speedup 1.0000x reference)
//
#include <hip/hip_runtime.h>

// Problem constants (B, L, H, D, T) = (8, 4096, 8, 128, 128)
constexpr int B = 8;
constexpr int L = 4096;
constexpr int H = 8;
constexpr int D = 128;
constexpr int T = 128;

constexpr int ROW   = H * D;        // 1024 floats per (b, p) row
constexpr int ROW4  = ROW / 4;      // 256 float4 per row
constexpr long long KV_ELEMS = (long long)B * L * ROW;   // 33,554,432 floats per tensor
constexpr int TOTAL4 = (int)(KV_ELEMS / 4);              // 8,388,608 float4 per tensor

// ---------------------------------------------------------------------------
// Kernel 1: pure streaming copy. Each half of the grid owns ONE (src,dst)
// stream pair -> clean 1-read/1-write access pattern per wave, no branch,
// no index math beyond the grid-stride. Unroll x4 => 4 loads in flight.
// Per-tensor: 8,388,608 float4 / (2048 blk * 256 thr) = 16 per thread = 4 outer iters.
// ---------------------------------------------------------------------------
constexpr int COPY_BLOCKS_PER_TENSOR = 2048;

__global__ __launch_bounds__(256) void kv_copy(
    const float4* __restrict__ keys,
    const float4* __restrict__ values,
    float4* __restrict__ out_k,
    float4* __restrict__ out_v)
{
    const float4* __restrict__ src;
    float4* __restrict__ dst;
    int bid;
    if (blockIdx.x < COPY_BLOCKS_PER_TENSOR) {
        src = keys;   dst = out_k; bid = blockIdx.x;
    } else {
        src = values; dst = out_v; bid = blockIdx.x - COPY_BLOCKS_PER_TENSOR;
    }

    const int stride = COPY_BLOCKS_PER_TENSOR * 256;     // threads per tensor
    int i = bid * 256 + (int)threadIdx.x;

    // TOTAL4 / stride == 16 exactly -> 4 iterations of unroll-4, no bounds checks
    #pragma unroll
    for (int outer = 0; outer < 4; ++outer) {
        float4 a = src[i];
        float4 b = src[i + stride];
        float4 c = src[i + 2 * stride];
        float4 d = src[i + 3 * stride];
        dst[i]              = a;
        dst[i + stride]     = b;
        dst[i + 2 * stride] = c;
        dst[i + 3 * stride] = d;
        i += 4 * stride;
    }
}

// ---------------------------------------------------------------------------
// Kernel 2: patch the <= B*T updated rows from new_keys/new_values and write
// updated_lengths. One block per (b, t) candidate row; whole block skips
// uniformly when t >= new_lengths[b]. <= 4 MB of traffic.
// ---------------------------------------------------------------------------
__global__ __launch_bounds__(256) void kv_patch(
    const float4* __restrict__ new_keys,
    const float4* __restrict__ new_values,
    const int*    __restrict__ lengths,
    const int*    __restrict__ new_lengths,
    float4* __restrict__ out_k,
    float4* __restrict__ out_v,
    float*  __restrict__ out_len)
{
    const int b = blockIdx.x >> 7;     // / T
    const int t = blockIdx.x & (T - 1);

    if (t < new_lengths[b]) {
        const int l = lengths[b];      // l in [0,2048), t < 128 -> l+t < L
        const int c = threadIdx.x;     // 256 threads == ROW4
        const long long srci = ((long long)(b * T + t) << 8) + c;
        const long long dsti = ((long long)(b * L + l + t) << 8) + c;
        out_k[dsti] = new_keys[srci];
        out_v[dsti] = new_values[srci];
    }

    if (blockIdx.x == 0 && threadIdx.x < B) {
        const int bb = threadIdx.x;
        out_len[bb] = (float)(lengths[bb] + new_lengths[bb]);
    }
}

extern "C" void kernel_launch(void* const* d_in, const int* in_sizes, int n_in,
                              void* d_out, int out_size, void* d_ws, size_t ws_size,
                              hipStream_t stream)
{
    const float4* keys       = (const float4*)d_in[0];
    const float4* values     = (const float4*)d_in[1];
    const int*    lengths    = (const int*)   d_in[2];
    const float4* new_keys   = (const float4*)d_in[3];
    const float4* new_values = (const float4*)d_in[4];
    const int*    new_lengths= (const int*)   d_in[5];

    float*  out     = (float*)d_out;
    float4* out_k   = (float4*)out;
    float4* out_v   = (float4*)(out + KV_ELEMS);
    float*  out_len = out + 2 * KV_ELEMS;

    // 1) bulk copy: keys->out_k, values->out_v (branch-free streaming)
    kv_copy<<<2 * COPY_BLOCKS_PER_TENSOR, 256, 0, stream>>>(keys, values, out_k, out_v);

    // 2) overwrite the updated rows + write lengths (same stream -> ordered)
    kv_patch<<<B * T, 256, 0, stream>>>(new_keys, new_values, lengths, new_lengths,
                                        out_k, out_v, out_len);
}

// Round 3
// 110.411 us; speedup vs baseline: 1.3141x; 1.3141x over previous
//
#include <hip/hip_runtime.h>

// Problem constants (B, L, H, D, T) = (8, 4096, 8, 128, 128)
constexpr int B = 8;
constexpr int L = 4096;
constexpr int H = 8;
constexpr int D = 128;
constexpr int T = 128;

constexpr long long KV_ELEMS = (long long)B * L * H * D;   // 33,554,432 floats per tensor
constexpr size_t KV_BYTES = (size_t)KV_ELEMS * sizeof(float);  // 128 MiB

// ---------------------------------------------------------------------------
// Patch the <= B*T updated rows from new_keys/new_values and write
// updated_lengths. One block per (b, t) candidate row; whole block skips
// uniformly when t >= new_lengths[b]. <= 8 MB of traffic total.
// Runs AFTER the bulk D2D copies on the same stream.
// ---------------------------------------------------------------------------
__global__ __launch_bounds__(256) void kv_patch(
    const float4* __restrict__ new_keys,
    const float4* __restrict__ new_values,
    const int*    __restrict__ lengths,
    const int*    __restrict__ new_lengths,
    float4* __restrict__ out_k,
    float4* __restrict__ out_v,
    float*  __restrict__ out_len)
{
    const int b = blockIdx.x >> 7;     // / T
    const int t = blockIdx.x & (T - 1);

    if (t < new_lengths[b]) {
        const int l = lengths[b];      // l in [0,2048), t < 128 -> l+t < L
        const int c = threadIdx.x;     // 256 threads == 256 float4 per row
        const long long srci = ((long long)(b * T + t) << 8) + c;
        const long long dsti = ((long long)(b * L + l + t) << 8) + c;
        out_k[dsti] = new_keys[srci];
        out_v[dsti] = new_values[srci];
    }

    if (blockIdx.x == 0 && threadIdx.x < B) {
        const int bb = threadIdx.x;
        out_len[bb] = (float)(lengths[bb] + new_lengths[bb]);
    }
}

extern "C" void kernel_launch(void* const* d_in, const int* in_sizes, int n_in,
                              void* d_out, int out_size, void* d_ws, size_t ws_size,
                              hipStream_t stream)
{
    const void* keys        = d_in[0];
    const void* values      = d_in[1];
    const int*  lengths     = (const int*)d_in[2];
    const float4* new_keys  = (const float4*)d_in[3];
    const float4* new_values= (const float4*)d_in[4];
    const int*  new_lengths = (const int*)d_in[5];

    float*  out     = (float*)d_out;
    float4* out_k   = (float4*)out;
    float4* out_v   = (float4*)(out + KV_ELEMS);
    float*  out_len = out + 2 * KV_ELEMS;

    // 1) bulk copy via runtime blit (graph-capture-legal async d2d copies)
    hipMemcpyAsync(out_k, keys,   KV_BYTES, hipMemcpyDeviceToDevice, stream);
    hipMemcpyAsync(out_v, values, KV_BYTES, hipMemcpyDeviceToDevice, stream);

    // 2) overwrite the updated rows + write lengths (same stream -> ordered)
    kv_patch<<<B * T, 256, 0, stream>>>(new_keys, new_values, lengths, new_lengths,
                                        out_k, out_v, out_len);
}